// Round 6
// baseline (1735.406 us; speedup 1.0000x reference)
//
#include <hip/hip_runtime.h>
#include <hip/hip_bf16.h>

// Problem dims (fixed by reference). All global I/O is fp32.
#define BATCH 1024
#define DLAT  512
#define HHID  1024
#define TPTS  64
#define BD    (BATCH * DLAT)     // 524288

// Cooperative decomposition: 16 row-groups (64 rows) x 16 col-groups.
// 256 blocks @ 140 KB LDS -> exactly 1 block/CU -> exactly 32 blocks/XCD.
// The 140 KB LDS is LOAD-BEARING: it forces 1 block/CU so each XCD hosts
// exactly 32 blocks, which is what makes the XCD-local barrier/exchange sound.
#define NBLK 256
#define NTHR 512                 // 8 waves
#define RGN  16                  // blocks per row-group (and # col groups)

typedef __attribute__((ext_vector_type(8))) short short8;  // 8 bf16 (4 VGPRs)
typedef __attribute__((ext_vector_type(4))) float f32x4;   // MFMA C/D frag

__device__ __forceinline__ short f2bf(float x) {
    __hip_bfloat16 h = __float2bfloat16(x);
    return __builtin_bit_cast(short, h);
}
__device__ __forceinline__ float fast_tanh(float x) {
    // clamped exp-based tanh: |err| ~1e-7; clamp also kills any NaN/Inf
    x = fminf(9.f, fmaxf(-9.f, x));
    const float e = __expf(2.f * x);
    return (e - 1.f) / (e + 1.f);
}

// Row-group barrier for 16 SAME-XCD blocks — ROUND-2 PROVEN FORM, verbatim.
// (Round 3's hand-rolled signal/poll hung; bisect confirmed. DO NOT TOUCH.)
// Release: __syncthreads drains vmcnt(0) (write-through L1 => stores are in
//          the shared XCD L2) before tid0 signals.
// Acquire: buffer_inv = per-CU L1 invalidate only; NO device fence (round-1's
//          910 MB L2-writeback disaster).
__device__ __forceinline__ void rg_barrier(int* bar, int cidx, int target, int tid)
{
    __syncthreads();             // s_waitcnt vmcnt(0) lgkmcnt(0) + s_barrier
    if (tid == 0) {
        atomicAdd(&bar[cidx], 1);
        while (__hip_atomic_load(&bar[cidx], __ATOMIC_RELAXED,
                                 __HIP_MEMORY_SCOPE_AGENT) < target) {
            __builtin_amdgcn_s_sleep(2);
        }
    }
    __syncthreads();
    asm volatile("buffer_inv\n\ts_waitcnt vmcnt(0)" ::: "memory");  // L1 acquire
}

// ---------------------------------------------------------------------------
// Cooperative persistent ODE kernel.
//   block(rg,cg): rows [rg*64, rg*64+64), phase-A H-cols [cg*64,+64),
//                 phase-B z-cols [cg*32,+32).  rg is XCD-local by construction.
//   W1 slice lives in REGISTERS (32 short8/wave = 128 VGPRs). Rounds 4/5
//   proved the default 128-VGPR cap spills it to scratch (+50 MB WRITE_SIZE,
//   -24% perf) and that __launch_bounds__(512,2) does NOT raise the cap in
//   this toolchain (VGPR_Count stayed 128, codegen identical). This round
//   attaches the backend attribute amdgpu_waves_per_eu(2,2) directly:
//   min 2 waves/EU => allocator cap 512/2 = 256 VGPRs. Demand ~230 => no spill.
//   W2 slice [1024 x 32] stays in LDS.
//   Exchange buffers (global, bf16 MFMA-A fragment order, XCD-L2 resident):
//     zf: [64 row-tiles][16 k-tiles][64 lanes][8]   (1 MB)
//     Hf: [64 row-tiles][32 k-tiles][64 lanes][8]   (2 MB)
// mfma_f32_16x16x32_bf16 layouts (m89/m120-verified):
//   A[m=lane&15][k=(lane>>4)*8+j], B[k=(lane>>4)*8+j][n=lane&15]
//   C/D: col=lane&15, row=(lane>>4)*4+reg
// ---------------------------------------------------------------------------
__global__ __launch_bounds__(NTHR)
__attribute__((amdgpu_waves_per_eu(2, 2)))
void ode_coop(
    const float* __restrict__ z0, const float* __restrict__ t,
    const float* __restrict__ W1, const float* __restrict__ b1,
    const float* __restrict__ W2, const float* __restrict__ b2,
    short* __restrict__ zf, short* __restrict__ Hf,
    int* __restrict__ bar, int* __restrict__ xcnt,
    float* __restrict__ traj)
{
    __shared__ __align__(16) short W1L[4 * 16 * 64 * 8];  // 64 KB (read once -> regs)
    __shared__ __align__(16) short W2L[2 * 32 * 64 * 8];  // 64 KB [ct2][kt2][lane][j]
    __shared__ __align__(16) short Hst[8 * 64 * 8];       //  8 KB [rt*2+k2l][lane][j]
    __shared__ __align__(16) short zst[4 * 64 * 8];       //  4 KB [rt][lane][j]
    __shared__ float b1L[64];
    __shared__ float b2L[32];
    __shared__ int slotS;

    const int tid  = threadIdx.x;
    const int lane = tid & 63;
    const int w    = tid >> 6;       // wave 0..7
    const int q    = lane >> 4;
    const int cl   = lane & 15;

    // ---- role assignment from the REAL XCD id (same-XCD rg by construction) ----
    unsigned int xcc;
    asm("s_getreg_b32 %0, hwreg(HW_REG_XCC_ID)" : "=s"(xcc));
    xcc &= 7u;
    if (tid == 0) slotS = atomicAdd(&xcnt[xcc], 1);
    __syncthreads();
    const int slot = slotS & 31;               // 0..31 within this XCD
    const int rg   = (int)xcc * 2 + (slot >> 4);   // 0..15 row-group (XCD-local)
    const int cg   = slot & 15;                // 0..15 col-group
    const int cidx = rg * 32;                  // 128B-spaced barrier counters

    // ---- one-time: weight slices fp32 -> bf16 fragment order -> LDS ----
    for (int i = tid; i < 4 * 16 * 64; i += NTHR) {
        const int ct = i >> 10, kt = (i >> 6) & 15, l = i & 63;
        const int k0 = kt * 32 + (l >> 4) * 8;
        const int n  = cg * 64 + ct * 16 + (l & 15);
        short8 v;
#pragma unroll
        for (int j = 0; j < 8; ++j) v[j] = f2bf(W1[(size_t)(k0 + j) * HHID + n]);
        *(short8*)&W1L[i * 8] = v;
    }
    for (int i = tid; i < 2 * 32 * 64; i += NTHR) {
        const int ct = i >> 11, kt = (i >> 6) & 31, l = i & 63;
        const int k0 = kt * 32 + (l >> 4) * 8;
        const int n  = cg * 32 + ct * 16 + (l & 15);
        short8 v;
#pragma unroll
        for (int j = 0; j < 8; ++j) v[j] = f2bf(W2[(size_t)(k0 + j) * DLAT + n]);
        *(short8*)&W2L[i * 8] = v;
    }
    if (tid < 64)      b1L[tid]      = b1[cg * 64 + tid];
    else if (tid < 96) b2L[tid - 64] = b2[cg * 32 + (tid - 64)];

    // ---- ownership ----
    // phase A: wave -> output tile rows rt=w>>1, H-col pair c0=(w&1)*2
    // phase B: wave -> output tile (rt=w>>1, ct2=w&1); thread owns 4 fp32 z elems
    const int rt   = w >> 1;
    const int c0   = (w & 1) * 2;
    const int ct2b = w & 1;
    const int rowb = rg * 64 + rt * 16 + q * 4;     // + reg = global batch row
    const int nb   = cg * 32 + ct2b * 16 + cl;      // global z col
    const int clb  = ct2b * 16 + cl;                // local z col 0..31
    const int zsti = rt * 512 + ((clb >> 3) * 16 + q * 4) * 8 + (clb & 7); // + reg*8

    float zreg[4], kacc[4];
#pragma unroll
    for (int reg = 0; reg < 4; ++reg) {
        const float zv = z0[(size_t)(rowb + reg) * DLAT + nb];
        zreg[reg] = zv;
        traj[(size_t)(rowb + reg) * DLAT + nb] = zv;    // traj[0] exact fp32
        zst[zsti + reg * 8] = f2bf(zv);
    }
    __syncthreads();
    if (tid < 256) {   // zst -> zf (block's 4 KB slice), 16B/thread
        const int rr = tid >> 6, l = tid & 63;
        *(short8*)&zf[((size_t)(rg * 4 + rr) * 16 + cg) * 512 + l * 8] =
            *(const short8*)&zst[tid * 8];
    }

    int target = 0;
    target += RGN; rg_barrier(bar, cidx, target, tid);

    const short* zrow = zf + (size_t)(rg * 4 + rt) * 8192  + lane * 8;
    const short* hrow = Hf + (size_t)(rg * 4 + rt) * 16384 + lane * 8;
    const short* w1p  = &W1L[c0 * 8192 + lane * 8];
    const short* w2p  = &W2L[ct2b * 16384 + lane * 8];

    // ---- W1 fragments -> registers, permanently (128 VGPRs/wave). ----
    short8 w1r[32];
#pragma unroll
    for (int kt = 0; kt < 16; ++kt) {
        w1r[kt]      = *(const short8*)(w1p + kt * 512);
        w1r[16 + kt] = *(const short8*)(w1p + 8192 + kt * 512);
    }

    for (int step = 0; step < TPTS - 1; ++step) {
        const float dt = t[step + 1] - t[step];

        // traj[step] = z_step, hoisted from the previous iteration's stage-3
        // epilogue: issuing the HBM store HERE gives it all of phase A to
        // retire instead of serializing into the barrier-entry vmcnt(0) drain.
        if (step > 0) {
#pragma unroll
            for (int reg = 0; reg < 4; ++reg)
                traj[(size_t)step * BD + (size_t)(rowb + reg) * DLAT + nb] =
                    zreg[reg];
        }

#pragma unroll
        for (int stage = 0; stage < 4; ++stage) {
            // ============== phase A: H = tanh(z @ W1slice + b1) ==============
            {
                f32x4 acc0 = {0.f, 0.f, 0.f, 0.f};
                f32x4 acc1 = {0.f, 0.f, 0.f, 0.f};
#pragma unroll
                for (int kt = 0; kt < 16; ++kt) {
                    const short8 a = *(const short8*)(zrow + kt * 512);
                    acc0 = __builtin_amdgcn_mfma_f32_16x16x32_bf16(a, w1r[kt],      acc0, 0, 0, 0);
                    acc1 = __builtin_amdgcn_mfma_f32_16x16x32_bf16(a, w1r[16 + kt], acc1, 0, 0, 0);
                }
#pragma unroll
                for (int c = 0; c < 2; ++c) {
                    const int   cloc = (c0 + c) * 16 + cl;    // 0..63
                    const float bb   = b1L[cloc];
                    const f32x4 av   = c ? acc1 : acc0;
#pragma unroll
                    for (int reg = 0; reg < 4; ++reg) {
                        Hst[(rt * 2 + (cloc >> 5)) * 512 +
                            (((cloc & 31) >> 3) * 16 + q * 4 + reg) * 8 + (cloc & 7)] =
                            f2bf(fast_tanh(av[reg] + bb));
                    }
                }
            }
            __syncthreads();
            {   // Hst -> Hf (block's 8 KB slice), 16B/thread
                const int rr = tid >> 7, k2l = (tid >> 6) & 1, l = tid & 63;
                *(short8*)&Hf[((size_t)(rg * 4 + rr) * 32 + cg * 2 + k2l) * 512 + l * 8] =
                    *(const short8*)&Hst[tid * 8];
            }
            target += RGN; rg_barrier(bar, cidx, target, tid);

            // ============ phase B: kv = H @ W2slice + b2 ; RK4 update ========
            {
                f32x4 acce = {0.f, 0.f, 0.f, 0.f};
                f32x4 acco = {0.f, 0.f, 0.f, 0.f};
#pragma unroll
                for (int kt = 0; kt < 32; kt += 2) {
                    const short8 a0  = *(const short8*)(hrow + kt * 512);
                    const short8 a1  = *(const short8*)(hrow + kt * 512 + 512);
                    const short8 bb0 = *(const short8*)(w2p + kt * 512);
                    const short8 bb1 = *(const short8*)(w2p + kt * 512 + 512);
                    acce = __builtin_amdgcn_mfma_f32_16x16x32_bf16(a0, bb0, acce, 0, 0, 0);
                    acco = __builtin_amdgcn_mfma_f32_16x16x32_bf16(a1, bb1, acco, 0, 0, 0);
                }
                const float bb = b2L[clb];
#pragma unroll
                for (int reg = 0; reg < 4; ++reg) {
                    const float kv = acce[reg] + acco[reg] + bb;
                    float znext;
                    if (stage == 0) {
                        kacc[reg] = kv;        znext = zreg[reg] + 0.5f * dt * kv;
                    } else if (stage == 1) {
                        kacc[reg] += 2.f * kv; znext = zreg[reg] + 0.5f * dt * kv;
                    } else if (stage == 2) {
                        kacc[reg] += 2.f * kv; znext = zreg[reg] + dt * kv;
                    } else {
                        zreg[reg] += (dt * (1.f / 6.f)) * (kacc[reg] + kv);
                        znext = zreg[reg];
                    }
                    zst[zsti + reg * 8] = f2bf(znext);
                }
            }
            __syncthreads();
            if (tid < 256) {   // zst -> zf
                const int rr = tid >> 6, l = tid & 63;
                *(short8*)&zf[((size_t)(rg * 4 + rr) * 16 + cg) * 512 + l * 8] =
                    *(const short8*)&zst[tid * 8];
            }
            target += RGN; rg_barrier(bar, cidx, target, tid);
        }
    }

    // final state: traj[TPTS-1] = z_{63}
#pragma unroll
    for (int reg = 0; reg < 4; ++reg)
        traj[(size_t)(TPTS - 1) * BD + (size_t)(rowb + reg) * DLAT + nb] =
            zreg[reg];
}

// ---------------------------------------------------------------------------
extern "C" void kernel_launch(void* const* d_in, const int* in_sizes, int n_in,
                              void* d_out, int out_size, void* d_ws, size_t ws_size,
                              hipStream_t stream)
{
    (void)in_sizes; (void)n_in; (void)out_size; (void)ws_size;

    const float* z0 = (const float*)d_in[0];
    const float* t  = (const float*)d_in[1];
    const float* W1 = (const float*)d_in[2];
    const float* b1 = (const float*)d_in[3];
    const float* W2 = (const float*)d_in[4];
    const float* b2 = (const float*)d_in[5];
    float*       traj = (float*)d_out;

    // Workspace: zf (1 MB) | Hf (2 MB) | bar (2 KB) | xcnt (32 B)
    short* zf   = (short*)d_ws;
    short* Hf   = (short*)((char*)d_ws + (1u << 20));
    int*   bar  = (int*)((char*)d_ws + (3u << 20));
    int*   xcnt = (int*)((char*)d_ws + (3u << 20) + 2048);

    hipMemsetAsync(bar, 0, 16 * 32 * sizeof(int) + 8 * sizeof(int), stream);

    void* args[] = {&z0, &t, &W1, &b1, &W2, &b2, &zf, &Hf, &bar, &xcnt, &traj};
    hipLaunchCooperativeKernel((const void*)ode_coop, dim3(NBLK), dim3(NTHR),
                               args, 0, stream);
}

// Round 7
// 1393.541 us; speedup vs baseline: 1.2453x; 1.2453x over previous
//
#include <hip/hip_runtime.h>
#include <hip/hip_bf16.h>

// Problem dims (fixed by reference). All global I/O is fp32.
#define BATCH 1024
#define DLAT  512
#define HHID  1024
#define TPTS  64
#define BD    (BATCH * DLAT)     // 524288

// Cooperative decomposition: 16 row-groups (64 rows) x 16 col-groups.
// 256 blocks @ ~131 KB LDS -> exactly 1 block/CU -> exactly 32 blocks/XCD.
// LDS > 80 KB is LOAD-BEARING: it forces 1 block/CU so each XCD hosts exactly
// 32 blocks, which is what makes the XCD-local barrier/exchange sound.
#define NBLK 256
#define NTHR 512                 // 8 waves
#define RGN  16                  // blocks per row-group (and # col groups)

// NOTE (rounds 3-6 post-mortem): W1-in-registers needs ~230 VGPRs; the
// toolchain refuses to raise the 128-VGPR cap (__launch_bounds__(512,2) and
// amdgpu_waves_per_eu(2,2) both ignored -> w1r spilled to scratch, +50 MB
// WRITE_SIZE, -24% perf). W1 therefore stays in LDS. Do not retry.

typedef __attribute__((ext_vector_type(8))) short short8;  // 8 bf16 (4 VGPRs)
typedef __attribute__((ext_vector_type(4))) float f32x4;   // MFMA C/D frag

__device__ __forceinline__ short f2bf(float x) {
    __hip_bfloat16 h = __float2bfloat16(x);
    return __builtin_bit_cast(short, h);
}
__device__ __forceinline__ float fast_tanh(float x) {
    // clamped exp-based tanh: |err| ~1e-7; clamp also kills any NaN/Inf
    x = fminf(9.f, fmaxf(-9.f, x));
    const float e = __expf(2.f * x);
    return (e - 1.f) / (e + 1.f);
}

// Row-group barrier for 16 SAME-XCD blocks — ROUND-2 PROVEN FORM, verbatim.
// (Round 3's hand-rolled signal/poll hung; bisect confirmed. DO NOT TOUCH.)
// Release: __syncthreads drains vmcnt(0) (write-through L1 => stores are in
//          the shared XCD L2) before tid0 signals.
// Acquire: buffer_inv = per-CU L1 invalidate only; NO device fence (round-1's
//          910 MB L2-writeback disaster).
__device__ __forceinline__ void rg_barrier(int* bar, int cidx, int target, int tid)
{
    __syncthreads();             // s_waitcnt vmcnt(0) lgkmcnt(0) + s_barrier
    if (tid == 0) {
        atomicAdd(&bar[cidx], 1);
        while (__hip_atomic_load(&bar[cidx], __ATOMIC_RELAXED,
                                 __HIP_MEMORY_SCOPE_AGENT) < target) {
            __builtin_amdgcn_s_sleep(2);
        }
    }
    __syncthreads();
    asm volatile("buffer_inv\n\ts_waitcnt vmcnt(0)" ::: "memory");  // L1 acquire
}

// ---------------------------------------------------------------------------
// Cooperative persistent ODE kernel.
//   block(rg,cg): rows [rg*64, rg*64+64), phase-A H-cols [cg*64,+64),
//                 phase-B z-cols [cg*32,+32).  rg is XCD-local by construction.
//   W1 slice [512 x 64] + W2 slice [1024 x 32] live in LDS all 252 stages.
//   Exchange buffers (global, bf16 MFMA-A fragment order, XCD-L2 resident):
//     zf: [64 row-tiles][16 k-tiles][64 lanes][8]   (1 MB)
//     Hf: [64 row-tiles][32 k-tiles][64 lanes][8]   (2 MB)
//   Epilogues store H and z DIRECTLY to Hf/zf as 2B global stores (no LDS
//   staging, no copy loops, 2 fewer __syncthreads/stage). Bit-identical data.
// mfma_f32_16x16x32_bf16 layouts (m89/m120-verified):
//   A[m=lane&15][k=(lane>>4)*8+j], B[k=(lane>>4)*8+j][n=lane&15]
//   C/D: col=lane&15, row=(lane>>4)*4+reg
// ---------------------------------------------------------------------------
__global__ __launch_bounds__(NTHR) void ode_coop(
    const float* __restrict__ z0, const float* __restrict__ t,
    const float* __restrict__ W1, const float* __restrict__ b1,
    const float* __restrict__ W2, const float* __restrict__ b2,
    short* __restrict__ zf, short* __restrict__ Hf,
    int* __restrict__ bar, int* __restrict__ xcnt,
    float* __restrict__ traj)
{
    __shared__ __align__(16) short W1L[4 * 16 * 64 * 8];  // 64 KB [ct][kt][lane][j]
    __shared__ __align__(16) short W2L[2 * 32 * 64 * 8];  // 64 KB [ct2][kt2][lane][j]
    __shared__ float b1L[64];
    __shared__ float b2L[32];
    __shared__ int slotS;

    const int tid  = threadIdx.x;
    const int lane = tid & 63;
    const int w    = tid >> 6;       // wave 0..7
    const int q    = lane >> 4;
    const int cl   = lane & 15;

    // ---- role assignment from the REAL XCD id (same-XCD rg by construction) ----
    unsigned int xcc;
    asm("s_getreg_b32 %0, hwreg(HW_REG_XCC_ID)" : "=s"(xcc));
    xcc &= 7u;
    if (tid == 0) slotS = atomicAdd(&xcnt[xcc], 1);
    __syncthreads();
    const int slot = slotS & 31;               // 0..31 within this XCD
    const int rg   = (int)xcc * 2 + (slot >> 4);   // 0..15 row-group (XCD-local)
    const int cg   = slot & 15;                // 0..15 col-group
    const int cidx = rg * 32;                  // 128B-spaced barrier counters

    // ---- one-time: weight slices fp32 -> bf16 fragment order -> LDS ----
    for (int i = tid; i < 4 * 16 * 64; i += NTHR) {
        const int ct = i >> 10, kt = (i >> 6) & 15, l = i & 63;
        const int k0 = kt * 32 + (l >> 4) * 8;
        const int n  = cg * 64 + ct * 16 + (l & 15);
        short8 v;
#pragma unroll
        for (int j = 0; j < 8; ++j) v[j] = f2bf(W1[(size_t)(k0 + j) * HHID + n]);
        *(short8*)&W1L[i * 8] = v;
    }
    for (int i = tid; i < 2 * 32 * 64; i += NTHR) {
        const int ct = i >> 11, kt = (i >> 6) & 31, l = i & 63;
        const int k0 = kt * 32 + (l >> 4) * 8;
        const int n  = cg * 32 + ct * 16 + (l & 15);
        short8 v;
#pragma unroll
        for (int j = 0; j < 8; ++j) v[j] = f2bf(W2[(size_t)(k0 + j) * DLAT + n]);
        *(short8*)&W2L[i * 8] = v;
    }
    if (tid < 64)      b1L[tid]      = b1[cg * 64 + tid];
    else if (tid < 96) b2L[tid - 64] = b2[cg * 32 + (tid - 64)];

    // ---- ownership ----
    // phase A: wave -> output tile rows rt=w>>1, H-col pair c0=(w&1)*2
    // phase B: wave -> output tile (rt=w>>1, ct2=w&1); thread owns 4 fp32 z elems
    const int rt   = w >> 1;
    const int c0   = (w & 1) * 2;
    const int ct2b = w & 1;
    const int rowb = rg * 64 + rt * 16 + q * 4;     // + reg = global batch row
    const int nb   = cg * 32 + ct2b * 16 + cl;      // global z col
    const int clb  = ct2b * 16 + cl;                // local z col 0..31

    // Direct-store bases (short indices). zf element (thread, reg):
    //   ((rg*4+rt)*16 + cg)*512 + ((clb>>3)*16 + q*4 + reg)*8 + (clb&7)
    const size_t zbase = ((size_t)(rg * 4 + rt) * 16 + cg) * 512 +
                         (size_t)(((clb >> 3) * 16 + q * 4) * 8 + (clb & 7));
    // Hf element (thread, c, reg), colc = (c0+c)*16+cl:
    //   ((rg*4+rt)*32 + cg*2 + (colc>>5))*512
    //   + (((colc&31)>>3)*16 + q*4 + reg)*8 + (colc&7)
    size_t hbase[2];
#pragma unroll
    for (int c = 0; c < 2; ++c) {
        const int colc = (c0 + c) * 16 + cl;
        hbase[c] = ((size_t)(rg * 4 + rt) * 32 + cg * 2 + (colc >> 5)) * 512 +
                   (size_t)((((colc & 31) >> 3) * 16 + q * 4) * 8 + (colc & 7));
    }

    float zreg[4], kacc[4];
#pragma unroll
    for (int reg = 0; reg < 4; ++reg) {
        const float zv = z0[(size_t)(rowb + reg) * DLAT + nb];
        zreg[reg] = zv;
        traj[(size_t)(rowb + reg) * DLAT + nb] = zv;    // traj[0] exact fp32
        zf[zbase + reg * 8] = f2bf(zv);                 // direct 2B store
    }

    int target = 0;
    target += RGN; rg_barrier(bar, cidx, target, tid);

    const short* zrow = zf + (size_t)(rg * 4 + rt) * 8192  + lane * 8;
    const short* hrow = Hf + (size_t)(rg * 4 + rt) * 16384 + lane * 8;
    const short* w1p  = &W1L[c0 * 8192 + lane * 8];
    const short* w2p  = &W2L[ct2b * 16384 + lane * 8];

    for (int step = 0; step < TPTS - 1; ++step) {
        const float dt = t[step + 1] - t[step];

        // traj[step] = z_step, hoisted from the previous iteration's stage-3
        // epilogue: issuing the HBM store HERE gives it all of phase A to
        // retire instead of serializing into the barrier-entry vmcnt(0) drain.
        if (step > 0) {
#pragma unroll
            for (int reg = 0; reg < 4; ++reg)
                traj[(size_t)step * BD + (size_t)(rowb + reg) * DLAT + nb] =
                    zreg[reg];
        }

#pragma unroll
        for (int stage = 0; stage < 4; ++stage) {
            // ============== phase A: H = tanh(z @ W1slice + b1) ==============
            {
                f32x4 acc0 = {0.f, 0.f, 0.f, 0.f};
                f32x4 acc1 = {0.f, 0.f, 0.f, 0.f};
#pragma unroll
                for (int kt = 0; kt < 16; ++kt) {
                    const short8 a  = *(const short8*)(zrow + kt * 512);
                    const short8 bA = *(const short8*)(w1p + kt * 512);
                    const short8 bB = *(const short8*)(w1p + 8192 + kt * 512);
                    acc0 = __builtin_amdgcn_mfma_f32_16x16x32_bf16(a, bA, acc0, 0, 0, 0);
                    acc1 = __builtin_amdgcn_mfma_f32_16x16x32_bf16(a, bB, acc1, 0, 0, 0);
                }
                // epilogue: bias + tanh -> DIRECT 2B stores into Hf
#pragma unroll
                for (int c = 0; c < 2; ++c) {
                    const int   cloc = (c0 + c) * 16 + cl;    // 0..63
                    const float bb   = b1L[cloc];
                    const f32x4 av   = c ? acc1 : acc0;
#pragma unroll
                    for (int reg = 0; reg < 4; ++reg)
                        Hf[hbase[c] + reg * 8] = f2bf(fast_tanh(av[reg] + bb));
                }
            }
            target += RGN; rg_barrier(bar, cidx, target, tid);

            // ============ phase B: kv = H @ W2slice + b2 ; RK4 update ========
            {
                f32x4 acce = {0.f, 0.f, 0.f, 0.f};
                f32x4 acco = {0.f, 0.f, 0.f, 0.f};
#pragma unroll
                for (int kt = 0; kt < 32; kt += 2) {
                    const short8 a0  = *(const short8*)(hrow + kt * 512);
                    const short8 a1  = *(const short8*)(hrow + kt * 512 + 512);
                    const short8 bb0 = *(const short8*)(w2p + kt * 512);
                    const short8 bb1 = *(const short8*)(w2p + kt * 512 + 512);
                    acce = __builtin_amdgcn_mfma_f32_16x16x32_bf16(a0, bb0, acce, 0, 0, 0);
                    acco = __builtin_amdgcn_mfma_f32_16x16x32_bf16(a1, bb1, acco, 0, 0, 0);
                }
                const float bb = b2L[clb];
#pragma unroll
                for (int reg = 0; reg < 4; ++reg) {
                    const float kv = acce[reg] + acco[reg] + bb;
                    float znext;
                    if (stage == 0) {
                        kacc[reg] = kv;        znext = zreg[reg] + 0.5f * dt * kv;
                    } else if (stage == 1) {
                        kacc[reg] += 2.f * kv; znext = zreg[reg] + 0.5f * dt * kv;
                    } else if (stage == 2) {
                        kacc[reg] += 2.f * kv; znext = zreg[reg] + dt * kv;
                    } else {
                        zreg[reg] += (dt * (1.f / 6.f)) * (kacc[reg] + kv);
                        znext = zreg[reg];
                    }
                    zf[zbase + reg * 8] = f2bf(znext);   // direct 2B store
                }
            }
            target += RGN; rg_barrier(bar, cidx, target, tid);
        }
    }

    // final state: traj[TPTS-1] = z_{63}
#pragma unroll
    for (int reg = 0; reg < 4; ++reg)
        traj[(size_t)(TPTS - 1) * BD + (size_t)(rowb + reg) * DLAT + nb] =
            zreg[reg];
}

// ---------------------------------------------------------------------------
extern "C" void kernel_launch(void* const* d_in, const int* in_sizes, int n_in,
                              void* d_out, int out_size, void* d_ws, size_t ws_size,
                              hipStream_t stream)
{
    (void)in_sizes; (void)n_in; (void)out_size; (void)ws_size;

    const float* z0 = (const float*)d_in[0];
    const float* t  = (const float*)d_in[1];
    const float* W1 = (const float*)d_in[2];
    const float* b1 = (const float*)d_in[3];
    const float* W2 = (const float*)d_in[4];
    const float* b2 = (const float*)d_in[5];
    float*       traj = (float*)d_out;

    // Workspace: zf (1 MB) | Hf (2 MB) | bar (2 KB) | xcnt (32 B)
    short* zf   = (short*)d_ws;
    short* Hf   = (short*)((char*)d_ws + (1u << 20));
    int*   bar  = (int*)((char*)d_ws + (3u << 20));
    int*   xcnt = (int*)((char*)d_ws + (3u << 20) + 2048);

    hipMemsetAsync(bar, 0, 16 * 32 * sizeof(int) + 8 * sizeof(int), stream);

    void* args[] = {&z0, &t, &W1, &b1, &W2, &b2, &zf, &Hf, &bar, &xcnt, &traj};
    hipLaunchCooperativeKernel((const void*)ode_coop, dim3(NBLK), dim3(NTHR),
                               args, 0, stream);
}

// Round 8
// 1389.192 us; speedup vs baseline: 1.2492x; 1.0031x over previous
//
#include <hip/hip_runtime.h>
#include <hip/hip_bf16.h>

// Problem dims (fixed by reference). All global I/O is fp32.
#define BATCH 1024
#define DLAT  512
#define HHID  1024
#define TPTS  64
#define BD    (BATCH * DLAT)     // 524288

// Cooperative decomposition: 16 row-groups (64 rows) x 16 col-groups.
// 256 blocks @ ~153 KB LDS -> exactly 1 block/CU -> exactly 32 blocks/XCD.
// LDS > 80 KB is LOAD-BEARING: it forces 1 block/CU so each XCD hosts exactly
// 32 blocks, which is what makes the XCD-local barrier/exchange sound.
#define NBLK 256
#define NTHR 512                 // 8 waves
#define RGN  16                  // blocks per row-group (and # col groups)

// NOTE (rounds 3-6 post-mortem): W1-in-registers needs ~230 VGPRs; the
// toolchain refuses to raise the 128-VGPR cap (__launch_bounds__(512,2) and
// amdgpu_waves_per_eu(2,2) both ignored -> spill, +50 MB WRITE_SIZE, -24%).
// Do not retry. This round instead halves operand-bytes/FLOP by moving to
// 32x32x16 MFMA (same 1KB A + 1KB B per MFMA, 2x the FLOPs).

typedef __attribute__((ext_vector_type(8)))  short short8;   // 8 bf16
typedef __attribute__((ext_vector_type(16))) float f32x16;   // 32x32 C/D frag

__device__ __forceinline__ short f2bf(float x) {
    __hip_bfloat16 h = __float2bfloat16(x);
    return __builtin_bit_cast(short, h);
}
__device__ __forceinline__ float fast_tanh(float x) {
    x = fminf(9.f, fmaxf(-9.f, x));
    const float e = __expf(2.f * x);
    return (e - 1.f) / (e + 1.f);
}

// Row-group barrier for 16 SAME-XCD blocks — ROUND-2 PROVEN FORM, verbatim.
// (Round 3's hand-rolled signal/poll hung; bisect confirmed. DO NOT TOUCH.)
__device__ __forceinline__ void rg_barrier(int* bar, int cidx, int target, int tid)
{
    __syncthreads();             // s_waitcnt vmcnt(0) lgkmcnt(0) + s_barrier
    if (tid == 0) {
        atomicAdd(&bar[cidx], 1);
        while (__hip_atomic_load(&bar[cidx], __ATOMIC_RELAXED,
                                 __HIP_MEMORY_SCOPE_AGENT) < target) {
            __builtin_amdgcn_s_sleep(2);
        }
    }
    __syncthreads();
    asm volatile("buffer_inv\n\ts_waitcnt vmcnt(0)" ::: "memory");  // L1 acquire
}

// ---------------------------------------------------------------------------
// 32x32x16 bf16 MFMA layouts:
//   A[m = lane&31][k = (lane>>5)*8 + j]      (analog of m89's 16x16 A-layout)
//   B[k = (lane>>5)*8 + j][n = lane&31]
//   C/D: col = lane&31, row = (reg&3) + 8*(reg>>2) + 4*(lane>>5)  [m74/m101]
// Fragment buffers (global, bf16, XCD-L2 resident), K-tile = 16:
//   zf: per rg: [rt32:2][kt:32][lane:64][j:8]   (1 MB total)
//   Hf: per rg: [rt32:2][kt:64][lane:64][j:8]   (2 MB total)
// Phase A: 4 output tiles (2rt x 2ct), wave = tile*2 + khalf (K split in 2).
// Phase B: 2 output tiles (2rt x 1ct), wave = tile*4 + kq    (K split in 4).
// Partials reduced via 24 KB LDS Rbuf; epilogue rows are partitioned across
// the k-split waves so tanh/RK4 work stays balanced (no serial tail).
// All acc[] indexing is compile-time via unrolled wave-uniform dispatch.
// ---------------------------------------------------------------------------
__global__ __launch_bounds__(NTHR) void ode_coop(
    const float* __restrict__ z0, const float* __restrict__ t,
    const float* __restrict__ W1, const float* __restrict__ b1,
    const float* __restrict__ W2, const float* __restrict__ b2,
    short* __restrict__ zf, short* __restrict__ Hf,
    int* __restrict__ bar, int* __restrict__ xcnt,
    float* __restrict__ traj)
{
    __shared__ __align__(16) short W1L[32 * 2 * 64 * 8];  // 64 KB [kt][ct][lane][j]
    __shared__ __align__(16) short W2L[64 * 64 * 8];      // 64 KB [kt][lane][j]
    __shared__ float Rbuf[6144];                          // 24 KB k-split exchange
    __shared__ float b1L[64];
    __shared__ float b2L[32];
    __shared__ int slotS;

    const int tid  = threadIdx.x;
    const int lane = tid & 63;
    const int w    = tid >> 6;       // wave 0..7

    // ---- role assignment from the REAL XCD id (same-XCD rg by construction) ----
    unsigned int xcc;
    asm("s_getreg_b32 %0, hwreg(HW_REG_XCC_ID)" : "=s"(xcc));
    xcc &= 7u;
    if (tid == 0) slotS = atomicAdd(&xcnt[xcc], 1);
    __syncthreads();
    const int slot = slotS & 31;                   // 0..31 within this XCD
    const int rg   = (int)xcc * 2 + (slot >> 4);   // 0..15 row-group (XCD-local)
    const int cg   = slot & 15;                    // 0..15 col-group
    const int cidx = rg * 32;                      // 128B-spaced barrier counters

    // ---- one-time: weight slices fp32 -> bf16 32x32x16 B-frag order -> LDS ----
    for (int i = tid; i < 32 * 2 * 64; i += NTHR) {      // W1 slice [512 x 64]
        const int kt = i >> 7, ct = (i >> 6) & 1, l = i & 63;
        const int k0 = kt * 16 + (l >> 5) * 8;
        const int n  = cg * 64 + ct * 32 + (l & 31);
        short8 v;
#pragma unroll
        for (int j = 0; j < 8; ++j) v[j] = f2bf(W1[(size_t)(k0 + j) * HHID + n]);
        *(short8*)&W1L[i * 8] = v;
    }
    for (int i = tid; i < 64 * 64; i += NTHR) {          // W2 slice [1024 x 32]
        const int kt = i >> 6, l = i & 63;
        const int k0 = kt * 16 + (l >> 5) * 8;
        const int n  = cg * 32 + (l & 31);
        short8 v;
#pragma unroll
        for (int j = 0; j < 8; ++j) v[j] = f2bf(W2[(size_t)(k0 + j) * DLAT + n]);
        *(short8*)&W2L[i * 8] = v;
    }
    if (tid < 64)      b1L[tid]      = b1[cg * 64 + tid];
    else if (tid < 96) b2L[tid - 64] = b2[cg * 32 + (tid - 64)];

    // ---- wave roles ----
    const int tileA = w >> 1, khalf = w & 1;    // phase A: 4 tiles x 2 k-halves
    const int rtA = tileA >> 1, ctA = tileA & 1;
    const int tileB = w >> 2, kq = w & 3;       // phase B: 2 tiles x 4 k-quads
    const int col32 = lane & 31;
    const int hl4   = (lane >> 5) * 4;

    // phase-A Hf direct-store base: H col (local) = ctA*32+col32
    const int hcl = ctA * 32 + col32;
    const size_t hAbase = ((size_t)(rg * 2 + rtA) * 64 + cg * 4 + (hcl >> 4)) * 512
                        + (size_t)(((hcl >> 3) & 1) * 256 + (hcl & 7));
    // phase-B zf direct-store base: z col = cg*32+col32
    const size_t zBbase = ((size_t)(rg * 2 + tileB) * 32 + cg * 2 + (col32 >> 4)) * 512
                        + (size_t)(((col32 >> 3) & 1) * 256 + (col32 & 7));
    const int nbcol = cg * 32 + col32;
    // this thread's 4 owned z rows (contiguous): rown0 .. rown0+3
    const int rown0 = rg * 64 + tileB * 32 + kq * 8 + hl4;

    // ---- init: traj[0] (exact fp32) + zf bf16 fragments for this block's slice
    for (int e = tid; e < 64 * 32; e += NTHR) {
        const int row64 = e >> 5, c32 = e & 31;
        const float v = z0[(size_t)(rg * 64 + row64) * DLAT + cg * 32 + c32];
        traj[(size_t)(rg * 64 + row64) * DLAT + cg * 32 + c32] = v;
        zf[((size_t)(rg * 2 + (row64 >> 5)) * 32 + cg * 2 + (c32 >> 4)) * 512 +
           ((c32 >> 3) & 1) * 256 + (row64 & 31) * 8 + (c32 & 7)] = f2bf(v);
    }
    float zreg[4], kacc[4];
#pragma unroll
    for (int i = 0; i < 4; ++i)
        zreg[i] = z0[(size_t)(rown0 + i) * DLAT + nbcol];

    int target = 0;
    target += RGN; rg_barrier(bar, cidx, target, tid);

    const short* zA  = zf + ((size_t)(rg * 2 + rtA) * 32 + khalf * 16) * 512 + lane * 8;
    const short* hB  = Hf + ((size_t)(rg * 2 + tileB) * 64 + kq * 16) * 512 + lane * 8;
    const short* w1p = &W1L[((khalf * 16) * 2 + ctA) * 512 + lane * 8];
    const short* w2p = &W2L[(kq * 16) * 512 + lane * 8];

    for (int step = 0; step < TPTS - 1; ++step) {
        const float dt = t[step + 1] - t[step];

        // traj[step] hoisted: HBM stores retire under phase A, not in a drain
        if (step > 0) {
#pragma unroll
            for (int i = 0; i < 4; ++i)
                traj[(size_t)step * BD + (size_t)(rown0 + i) * DLAT + nbcol] =
                    zreg[i];
        }

#pragma unroll
        for (int stage = 0; stage < 4; ++stage) {
            // ============ phase A: H = tanh(z @ W1slice + b1), K split x2 =====
            {
                f32x16 acc = {0.f,0.f,0.f,0.f, 0.f,0.f,0.f,0.f,
                              0.f,0.f,0.f,0.f, 0.f,0.f,0.f,0.f};
#pragma unroll
                for (int kt = 0; kt < 16; ++kt) {
                    const short8 a = *(const short8*)(zA  + kt * 512);
                    const short8 b = *(const short8*)(w1p + kt * 1024);
                    acc = __builtin_amdgcn_mfma_f32_32x32x16_bf16(a, b, acc, 0, 0, 0);
                }
                // write the OTHER half's rows to Rbuf (one writer per (tile,r))
#pragma unroll
                for (int h = 0; h < 2; ++h) if (khalf == h) {
#pragma unroll
                    for (int i = 0; i < 8; ++i) {
                        const int r = (1 - h) * 8 + i;
                        Rbuf[(tileA * 16 + r) * 64 + lane] = acc[r];
                    }
                }
                __syncthreads();
                // own half: sum partner partial, bias+tanh, direct store to Hf
#pragma unroll
                for (int h = 0; h < 2; ++h) if (khalf == h) {
#pragma unroll
                    for (int i = 0; i < 8; ++i) {
                        const int r     = h * 8 + i;
                        const int row32 = (i & 3) + 8 * (h * 2 + (i >> 2)) + hl4;
                        const float v = acc[r] + Rbuf[(tileA * 16 + r) * 64 + lane]
                                      + b1L[hcl];
                        Hf[hAbase + row32 * 8] = f2bf(fast_tanh(v));
                    }
                }
            }
            target += RGN; rg_barrier(bar, cidx, target, tid);

            // ======== phase B: kv = H @ W2slice + b2 (K split x4); RK4 ========
            {
                f32x16 acc = {0.f,0.f,0.f,0.f, 0.f,0.f,0.f,0.f,
                              0.f,0.f,0.f,0.f, 0.f,0.f,0.f,0.f};
#pragma unroll
                for (int kt = 0; kt < 16; ++kt) {
                    const short8 a = *(const short8*)(hB  + kt * 512);
                    const short8 b = *(const short8*)(w2p + kt * 512);
                    acc = __builtin_amdgcn_mfma_f32_32x32x16_bf16(a, b, acc, 0, 0, 0);
                }
                // write partials for rows owned by OTHER kq waves (3 slots/(tile,r))
#pragma unroll
                for (int g = 0; g < 4; ++g) if (kq == g) {
#pragma unroll
                    for (int r = 0; r < 16; ++r) {
                        const int og = r >> 2;
                        if (og != g) {
                            const int s = (g < og) ? g : g - 1;
                            Rbuf[((tileB * 16 + r) * 3 + s) * 64 + lane] = acc[r];
                        }
                    }
                }
                __syncthreads();
                float kvp[4];
#pragma unroll
                for (int g = 0; g < 4; ++g) if (kq == g) {
#pragma unroll
                    for (int i = 0; i < 4; ++i) {
                        const int r = g * 4 + i;
                        kvp[i] = acc[r]
                               + Rbuf[((tileB * 16 + r) * 3 + 0) * 64 + lane]
                               + Rbuf[((tileB * 16 + r) * 3 + 1) * 64 + lane]
                               + Rbuf[((tileB * 16 + r) * 3 + 2) * 64 + lane];
                    }
                }
#pragma unroll
                for (int i = 0; i < 4; ++i) {
                    const float kv = kvp[i] + b2L[col32];
                    float znext;
                    if (stage == 0) {
                        kacc[i] = kv;        znext = zreg[i] + 0.5f * dt * kv;
                    } else if (stage == 1) {
                        kacc[i] += 2.f * kv; znext = zreg[i] + 0.5f * dt * kv;
                    } else if (stage == 2) {
                        kacc[i] += 2.f * kv; znext = zreg[i] + dt * kv;
                    } else {
                        zreg[i] += (dt * (1.f / 6.f)) * (kacc[i] + kv);
                        znext = zreg[i];
                    }
                    zf[zBbase + (size_t)(kq * 8 + hl4 + i) * 8] = f2bf(znext);
                }
            }
            target += RGN; rg_barrier(bar, cidx, target, tid);
        }
    }

    // final state: traj[TPTS-1] = z_{63}
#pragma unroll
    for (int i = 0; i < 4; ++i)
        traj[(size_t)(TPTS - 1) * BD + (size_t)(rown0 + i) * DLAT + nbcol] =
            zreg[i];
}

// ---------------------------------------------------------------------------
extern "C" void kernel_launch(void* const* d_in, const int* in_sizes, int n_in,
                              void* d_out, int out_size, void* d_ws, size_t ws_size,
                              hipStream_t stream)
{
    (void)in_sizes; (void)n_in; (void)out_size; (void)ws_size;

    const float* z0 = (const float*)d_in[0];
    const float* t  = (const float*)d_in[1];
    const float* W1 = (const float*)d_in[2];
    const float* b1 = (const float*)d_in[3];
    const float* W2 = (const float*)d_in[4];
    const float* b2 = (const float*)d_in[5];
    float*       traj = (float*)d_out;

    // Workspace: zf (1 MB) | Hf (2 MB) | bar (2 KB) | xcnt (32 B)
    short* zf   = (short*)d_ws;
    short* Hf   = (short*)((char*)d_ws + (1u << 20));
    int*   bar  = (int*)((char*)d_ws + (3u << 20));
    int*   xcnt = (int*)((char*)d_ws + (3u << 20) + 2048);

    hipMemsetAsync(bar, 0, 16 * 32 * sizeof(int) + 8 * sizeof(int), stream);

    void* args[] = {&z0, &t, &W1, &b1, &W2, &b2, &zf, &Hf, &bar, &xcnt, &traj};
    hipLaunchCooperativeKernel((const void*)ode_coop, dim3(NBLK), dim3(NTHR),
                               args, 0, stream);
}